// Round 4
// baseline (85911.676 us; speedup 1.0000x reference)
//
#include <hip/hip_runtime.h>
#include <math.h>

namespace {
constexpr int Bn = 128, Ln = 256, En = 512, Hn = 512;

// ws layout (float offsets). First 8192 floats = barrier flags (256 x 64B) + gen.
constexpr long WS_CTX  = 8192;                       // [B][L][H] = ctx[b,l,o]
constexpr long WS_H    = WS_CTX + (long)Bn * Ln * Hn;
constexpr long WS_C    = WS_H   + (long)Bn * Hn;
constexpr long WS_HL   = WS_C   + (long)Bn * Hn;
constexpr long WS_INP  = WS_HL  + (long)Bn * Hn;
constexpr long WS_HS   = WS_INP + (long)Bn * Hn;
constexpr long WS_DEC  = WS_HS  + (long)Bn * Hn;
constexpr long WS_ATT  = WS_DEC + (long)Bn * En;
constexpr long WS_MASK = WS_ATT + (long)Bn * Ln;
constexpr long WS_WTA  = WS_MASK + (long)Bn * Ln;    // Wa_in^T [512k][512o]
constexpr long WS_WTO  = WS_WTA + (long)512 * 512;   // Who^T  [1024k][512o]

// out layout (float offsets)
constexpr long OUT_PTR = (long)Bn * Ln * Ln;   // 8388608
constexpr long OUT_HF  = OUT_PTR + (long)Bn * Ln;
constexpr long OUT_CF  = OUT_HF + (long)Bn * Hn;
}

struct PParams {
  const float *emb, *dec0, *h0, *c0;
  const float *Wih, *bih, *Whh, *bhh;
  const float *Who, *bho, *Wa_in, *ba_in, *V;
  float *ws, *out;
};

// ---------- flag-array grid barrier (no RMW serialization) -------------------
__device__ __forceinline__ void gsync(unsigned* ub, unsigned target, int blk) {
  __syncthreads();
  unsigned* flags = ub;            // flags[b] at ub[b*16] (64B apart)
  unsigned* gen   = ub + 4096;
  const int t = threadIdx.x;
  if (blk == 0) {
    for (;;) {
      unsigned v = (t > 0 && t < 256)
          ? __hip_atomic_load(&flags[t * 16], __ATOMIC_RELAXED, __HIP_MEMORY_SCOPE_AGENT)
          : target;
      int cnt = __syncthreads_count((int)(v >= target));
      if (cnt == (int)blockDim.x) break;
      __builtin_amdgcn_s_sleep(2);
    }
    __builtin_amdgcn_fence(__ATOMIC_ACQUIRE, "agent");
    if (t == 0)
      __hip_atomic_store(gen, target, __ATOMIC_RELEASE, __HIP_MEMORY_SCOPE_AGENT);
  } else {
    if (t == 0) {
      __hip_atomic_store(&flags[blk * 16], target, __ATOMIC_RELEASE, __HIP_MEMORY_SCOPE_AGENT);
      while (__hip_atomic_load(gen, __ATOMIC_RELAXED, __HIP_MEMORY_SCOPE_AGENT) < target)
        __builtin_amdgcn_s_sleep(2);
      (void)__hip_atomic_load(gen, __ATOMIC_ACQUIRE, __HIP_MEMORY_SCOPE_AGENT);
    }
  }
  __syncthreads();
}

// ---------------- ctx precompute: ctx[b,l,o] = context[b,l,:]·Wa_ctx[o,:] + ba_ctx[o]
__launch_bounds__(256)
__global__ void ctx_precompute(const float* __restrict__ context,
                               const float* __restrict__ Wa,
                               const float* __restrict__ ba,
                               float* __restrict__ ws) {
  __shared__ __align__(16) float As[16 * 68];
  __shared__ __align__(16) float Wsm[16 * 68];
  float* ctx = ws + WS_CTX;
  const int mt = blockIdx.x >> 3;
  const int nt = blockIdx.x & 7;
  const int t = threadIdx.x;
  const int tm = t & 15, tn = t >> 4;
  float acc00=0,acc01=0,acc02=0,acc03=0, acc10=0,acc11=0,acc12=0,acc13=0;
  float acc20=0,acc21=0,acc22=0,acc23=0, acc30=0,acc31=0,acc32=0,acc33=0;

  for (int kt = 0; kt < 32; ++kt) {
    __syncthreads();
    {
      const int m = t >> 2, k4 = t & 3;
      float4 a = *(const float4*)(context + (size_t)(mt * 64 + m) * 512 + kt * 16 + k4 * 4);
      As[(k4*4+0)*68 + m] = a.x; As[(k4*4+1)*68 + m] = a.y;
      As[(k4*4+2)*68 + m] = a.z; As[(k4*4+3)*68 + m] = a.w;
      float4 w = *(const float4*)(Wa + (size_t)(nt * 64 + m) * 512 + kt * 16 + k4 * 4);
      Wsm[(k4*4+0)*68 + m] = w.x; Wsm[(k4*4+1)*68 + m] = w.y;
      Wsm[(k4*4+2)*68 + m] = w.z; Wsm[(k4*4+3)*68 + m] = w.w;
    }
    __syncthreads();
#pragma unroll
    for (int k = 0; k < 16; ++k) {
      float4 a4 = *(const float4*)(As + k * 68 + tm * 4);
      float4 b4 = *(const float4*)(Wsm + k * 68 + tn * 4);
      acc00 = fmaf(a4.x, b4.x, acc00); acc01 = fmaf(a4.x, b4.y, acc01);
      acc02 = fmaf(a4.x, b4.z, acc02); acc03 = fmaf(a4.x, b4.w, acc03);
      acc10 = fmaf(a4.y, b4.x, acc10); acc11 = fmaf(a4.y, b4.y, acc11);
      acc12 = fmaf(a4.y, b4.z, acc12); acc13 = fmaf(a4.y, b4.w, acc13);
      acc20 = fmaf(a4.z, b4.x, acc20); acc21 = fmaf(a4.z, b4.y, acc21);
      acc22 = fmaf(a4.z, b4.z, acc22); acc23 = fmaf(a4.z, b4.w, acc23);
      acc30 = fmaf(a4.w, b4.x, acc30); acc31 = fmaf(a4.w, b4.y, acc31);
      acc32 = fmaf(a4.w, b4.z, acc32); acc33 = fmaf(a4.w, b4.w, acc33);
    }
  }
  const int col = nt * 64 + tn * 4;
  float4 bias = *(const float4*)(ba + col);
  float4 o0 = {acc00 + bias.x, acc01 + bias.y, acc02 + bias.z, acc03 + bias.w};
  float4 o1 = {acc10 + bias.x, acc11 + bias.y, acc12 + bias.z, acc13 + bias.w};
  float4 o2 = {acc20 + bias.x, acc21 + bias.y, acc22 + bias.z, acc23 + bias.w};
  float4 o3 = {acc30 + bias.x, acc31 + bias.y, acc32 + bias.z, acc33 + bias.w};
  const size_t base = (size_t)(mt * 64 + tm * 4) * 512 + col;
  *(float4*)(ctx + base + 0 * 512) = o0;
  *(float4*)(ctx + base + 1 * 512) = o1;
  *(float4*)(ctx + base + 2 * 512) = o2;
  *(float4*)(ctx + base + 3 * 512) = o3;
}

// -------- one-time weight transpose: WTA[k][o]=Wa_in[o][k], WTO[k][o]=Who[o][k]
__launch_bounds__(256)
__global__ void transpose_w(const float* __restrict__ Wa_in,
                            const float* __restrict__ Who,
                            float* __restrict__ ws) {
  __shared__ float tile[64][65];
  const int bid = blockIdx.x, t = threadIdx.x;
  const float* src; float* dst; int K, rt, ct;
  if (bid < 64) { src = Wa_in; dst = ws + WS_WTA; K = 512;  rt = bid >> 3;        ct = bid & 7;  }
  else          { src = Who;   dst = ws + WS_WTO; K = 1024; rt = (bid - 64) >> 4; ct = (bid - 64) & 15; }
  const int lr = t >> 6, lc = t & 63;
#pragma unroll
  for (int i = 0; i < 16; ++i) {
    int r = i * 4 + lr;
    tile[r][lc] = src[(size_t)(rt * 64 + r) * K + ct * 64 + lc];
  }
  __syncthreads();
#pragma unroll
  for (int i = 0; i < 16; ++i) {
    int r = i * 4 + lr;   // r = k within tile now
    dst[(size_t)(ct * 64 + r) * 512 + rt * 64 + lc] = tile[lc][r];
  }
}

// --------- persistent main loop: 256 blocks x 1024 threads (1/CU, 16 waves) --
// R2's exact 5-phase structure; B/F use pre-transposed weights (coalesced,
// deep-unrolled), E-hs uses order-preserving compaction (same fmaf
// subsequence as the al!=0 branch, but pipelined unconditional loads).
__launch_bounds__(1024, 4)
__global__ void pdecoder_main(PParams p) {
  __shared__ __align__(16) float smem[8192];   // 32 KB

  float* ws = p.ws;
  unsigned* ub = (unsigned*)ws;
  unsigned tgt = 0;
  const int t = threadIdx.x, blk = blockIdx.x;

  float* ctx    = ws + WS_CTX;
  float* hbuf   = ws + WS_H;
  float* cbuf   = ws + WS_C;
  float* hlbuf  = ws + WS_HL;
  float* inpbuf = ws + WS_INP;
  float* hsbuf  = ws + WS_HS;
  float* decbuf = ws + WS_DEC;
  float* attbuf = ws + WS_ATT;
  float* maskbuf= ws + WS_MASK;
  const float* WTA = ws + WS_WTA;
  const float* WTO = ws + WS_WTO;

  // ---- init state (ws poisoned every call) ----
  {
    int idx = blk * 1024 + t;
    if (idx < Bn * Hn) { hbuf[idx] = p.h0[idx]; cbuf[idx] = p.c0[idx]; }
    if (idx < Bn * En) decbuf[idx] = p.dec0[idx];
    if (idx < Bn * Ln) maskbuf[idx] = 1.0f;
  }
  gsync(ub, ++tgt, blk);

  for (int step = 0; step < Ln; ++step) {
    // ===== Phase A: gates = dec@Wih^T + h@Whh^T + b; LSTM elementwise =======
    // (verbatim R2 math: conflict-free 8-row swizzled tile, K sequential)
    {
      const int bt = blk >> 4, gt = blk & 15;
      const int bi = t & 7, cg = t >> 3;          // cg 0..127 = g*32 + j0
      const int j0 = cg & 31, g = cg >> 5;
      const int gc = g * 512 + gt * 32 + j0;
      const int r = t >> 6, ks = t & 63;          // staging (t<512): row, col
      float4* Xs = (float4*)smem;                 // [8][64] float4, swizzled
      float acc = 0.f;
      float4 pre;
      if (t < 512) pre = ((const float4*)(decbuf + (size_t)(bt * 8 + r) * 512))[ks];
#pragma unroll
      for (int kt = 0; kt < 4; ++kt) {
        __syncthreads();
        if (t < 512) Xs[r * 64 + (ks ^ r)] = pre;
        __syncthreads();
        if (t < 512 && kt < 3) {
          const float* src = (kt + 1 < 2) ? decbuf : hbuf;
          pre = ((const float4*)(src + (size_t)(bt * 8 + r) * 512 + ((kt + 1) & 1) * 256))[ks];
        }
        const float4* W4 = (const float4*)(((kt < 2) ? p.Wih : p.Whh) + (size_t)gc * 512 + (kt & 1) * 256);
#pragma unroll 16
        for (int k4 = 0; k4 < 64; ++k4) {
          float4 x = Xs[bi * 64 + (k4 ^ bi)];
          float4 w = W4[k4];
          acc = fmaf(x.x, w.x, acc); acc = fmaf(x.y, w.y, acc);
          acc = fmaf(x.z, w.z, acc); acc = fmaf(x.w, w.w, acc);
        }
      }
      __syncthreads();
      float* gs = smem + 4096;                    // [8][132]
      gs[bi * 132 + cg] = acc + p.bih[gc] + p.bhh[gc];
      __syncthreads();
      if (t < 256) {
        const int j = t & 31, bi2 = t >> 5;
        float ig = gs[bi2 * 132 + j];
        float fg = gs[bi2 * 132 + 32 + j];
        float gg = gs[bi2 * 132 + 64 + j];
        float og = gs[bi2 * 132 + 96 + j];
        const int b = bt * 8 + bi2, h = gt * 32 + j;
        float cold = cbuf[b * 512 + h];
        float is = 1.f / (1.f + expf(-ig));
        float fs = 1.f / (1.f + expf(-fg));
        float os = 1.f / (1.f + expf(-og));
        float ct = fs * cold + is * tanhf(gg);
        float hl = os * tanhf(ct);
        cbuf[b * 512 + h] = ct;
        hlbuf[b * 512 + h] = hl;
      }
    }
    gsync(ub, ++tgt, blk);

    // ===== Phase B: inp = h_lstm @ Wa_in^T + ba_in (coalesced WTA) ==========
    // 2 blocks/b, 256 o's each. Thread-per-o, k 0..511 ascending (exact R2
    // chain: same values, same order), lanes contiguous in o -> coalesced.
    {
      const int b = blk >> 1, oh = blk & 1;
      float* hl_s = smem;
      if (t < 128) ((float4*)hl_s)[t] = ((const float4*)(hlbuf + (size_t)b * 512))[t];
      __syncthreads();
      if (t < 256) {
        const int o = oh * 256 + t;
        const float* Wc = WTA + o;
        float acc = 0.f;
#pragma unroll 32
        for (int k = 0; k < 512; ++k)
          acc = fmaf(hl_s[k], Wc[(size_t)k * 512], acc);
        inpbuf[b * 512 + o] = acc + p.ba_in[o];
      }
    }
    gsync(ub, ++tgt, blk);

    // ===== Phase C: att[b,l] = sum_h V[h] tanh(inp+ctx), mask-skipped =======
    // (R2-verbatim: 2 blocks per b, 128 l each, 16 waves x 8 l.)
    {
      const int b = blk >> 1, ph = blk & 1;
      float* inp_s = smem;          // 512
      float* V_s   = smem + 512;    // 512
      if (t < 512) { inp_s[t] = inpbuf[b * 512 + t]; V_s[t] = p.V[t]; }
      __syncthreads();
      const int w = t >> 6, lane = t & 63;
      const float4* inp4 = (const float4*)inp_s;
      const float4* V4   = (const float4*)V_s;
      float4 i0 = inp4[lane],  i1 = inp4[64 + lane];
      float4 v0 = V4[lane],    v1 = V4[64 + lane];
      for (int i = 0; i < 8; ++i) {
        const int l = ph * 128 + w * 8 + i;
        float msk = maskbuf[b * 256 + l];      // wave-uniform
        if (msk == 0.f) {
          if (lane == 0) attbuf[b * 256 + l] = -INFINITY;
          continue;
        }
        const float4* row = (const float4*)(ctx + (size_t)(b * 256 + l) * 512);
        float4 c0 = row[lane], c1 = row[64 + lane];
        float a;
        a = v0.x * tanhf(i0.x + c0.x);
        a = fmaf(v0.y, tanhf(i0.y + c0.y), a);
        a = fmaf(v0.z, tanhf(i0.z + c0.z), a);
        a = fmaf(v0.w, tanhf(i0.w + c0.w), a);
        a = fmaf(v1.x, tanhf(i1.x + c1.x), a);
        a = fmaf(v1.y, tanhf(i1.y + c1.y), a);
        a = fmaf(v1.z, tanhf(i1.z + c1.z), a);
        a = fmaf(v1.w, tanhf(i1.w + c1.w), a);
#pragma unroll
        for (int off = 32; off > 0; off >>= 1) a += __shfl_xor(a, off, 64);
        if (lane == 0) attbuf[b * 256 + l] = a;
      }
    }
    gsync(ub, ++tgt, blk);

    // ===== Phase E: tree softmax + argmax + outputs + compacted hs ==========
    {
      const int b = blk >> 1, ph = blk & 1;
      float* att_s   = smem;               // 256 (reused as scan after alpha)
      float* val_s   = smem + 256;         // 256
      int*   idx_s   = (int*)(smem + 512); // 256 (argmax idx, then compact list)
      float* alpha_s = smem + 768;         // 256
      float* part_s  = smem + 1024;        // 256
      if (t < 256) {
        float a = attbuf[b * 256 + t];
        att_s[t] = a; val_s[t] = a; idx_s[t] = t;
      }
      __syncthreads();
      for (int s = 128; s > 0; s >>= 1) {
        if (t < s) {
          float v1 = val_s[t], v2 = val_s[t + s];
          int   i1 = idx_s[t], i2 = idx_s[t + s];
          if (v2 > v1 || (v2 == v1 && i2 < i1)) { val_s[t] = v2; idx_s[t] = i2; }
        }
        __syncthreads();
      }
      const float m = val_s[0];
      const int am = idx_s[0];
      __syncthreads();
      if (t < 256) {
        float e = expf(att_s[t] - m);   // exp(-inf)=0 for masked
        alpha_s[t] = e; val_s[t] = e;
      }
      __syncthreads();
      for (int s = 128; s > 0; s >>= 1) {
        if (t < s) val_s[t] += val_s[t + s];
        __syncthreads();
      }
      const float Z = val_s[0];
      __syncthreads();
      if (t < 256) alpha_s[t] = alpha_s[t] / Z;
      __syncthreads();
      if (ph == 0) {
        if (t < 256) p.out[(size_t)b * Ln * Ln + (size_t)step * Ln + t] = alpha_s[t];
        if (t == 0) {
          p.out[OUT_PTR + (size_t)b * Ln + step] = (float)am;
          maskbuf[b * 256 + am] = 0.f;
        }
        if (t < 512) decbuf[b * 512 + t] = p.emb[((size_t)(b * 256) + am) * 512 + t];
      }
      // ---- order-preserving compaction of {l : alpha_s[l] != 0} -----------
      // Same skip condition as R2's branch (al != 0), so the per-(h,lp) fmaf
      // subsequence is bit-identical; loads become unconditional + pipelined.
      if (t < 256) att_s[t] = (alpha_s[t] != 0.f) ? 1.f : 0.f;
      __syncthreads();
      for (int s = 1; s < 256; s <<= 1) {          // Hillis-Steele inclusive
        float add = 0.f;
        if (t < 256 && t >= s) add = att_s[t - s];
        __syncthreads();
        if (t < 256) att_s[t] += add;
        __syncthreads();
      }
      if (t < 256 && alpha_s[t] != 0.f) idx_s[(int)att_s[t] - 1] = t;
      __syncthreads();
      const int cnt0 = (int)att_s[127];
      const int cntA = (int)att_s[255];
      // hs[b, ph*256+hi] over 2 l-halves (compact [0,cnt0) and [cnt0,cntA)),
      // pairwise combined — R2-exact order.
      const int hi = t & 255, lp = (t >> 8) & 1;
      const int h = ph * 256 + hi;
      float acc = 0.f;
      if (t < 512) {
        const float* cb = ctx + (size_t)b * 256 * 512 + h;
        int j = lp ? cnt0 : 0;
        const int jhi = lp ? cntA : cnt0;
        for (; j + 8 <= jhi; j += 8) {
          int l0 = idx_s[j+0], l1 = idx_s[j+1], l2 = idx_s[j+2], l3 = idx_s[j+3];
          int l4 = idx_s[j+4], l5 = idx_s[j+5], l6 = idx_s[j+6], l7 = idx_s[j+7];
          float a0 = alpha_s[l0], a1 = alpha_s[l1], a2 = alpha_s[l2], a3 = alpha_s[l3];
          float a4 = alpha_s[l4], a5 = alpha_s[l5], a6 = alpha_s[l6], a7 = alpha_s[l7];
          float c0 = cb[(size_t)l0 * 512], c1 = cb[(size_t)l1 * 512];
          float c2 = cb[(size_t)l2 * 512], c3 = cb[(size_t)l3 * 512];
          float c4 = cb[(size_t)l4 * 512], c5 = cb[(size_t)l5 * 512];
          float c6 = cb[(size_t)l6 * 512], c7 = cb[(size_t)l7 * 512];
          acc = fmaf(a0, c0, acc); acc = fmaf(a1, c1, acc);
          acc = fmaf(a2, c2, acc); acc = fmaf(a3, c3, acc);
          acc = fmaf(a4, c4, acc); acc = fmaf(a5, c5, acc);
          acc = fmaf(a6, c6, acc); acc = fmaf(a7, c7, acc);
        }
        for (; j < jhi; ++j) {
          int l = idx_s[j];
          acc = fmaf(alpha_s[l], cb[(size_t)l * 512], acc);
        }
      }
      if (t < 512 && lp == 1) part_s[hi] = acc;
      __syncthreads();
      if (t < 512 && lp == 0) hsbuf[(size_t)b * 512 + h] = acc + part_s[hi];
    }
    gsync(ub, ++tgt, blk);

    // ===== Phase F: h = tanh([hs, hl] @ Who^T + bho) — coalesced WTO ========
    // 2 blocks/b, 256 o's each; (o, kh) thread pairs, k ascending within each
    // kh half (exact R2 chain), lanes contiguous in o -> coalesced.
    {
      const int b = blk >> 1, oh = blk & 1;
      float* hs_s  = smem;           // 512
      float* hl_s  = smem + 512;     // 512
      float* partF = smem + 1024;    // 256
      if (t < 128) {
        ((float4*)hs_s)[t] = ((const float4*)(hsbuf + (size_t)b * 512))[t];
        ((float4*)hl_s)[t] = ((const float4*)(hlbuf + (size_t)b * 512))[t];
      }
      __syncthreads();
      float acc = 0.f;
      if (t < 512) {
        const int oj = t & 255, kh = t >> 8;
        const int o = oh * 256 + oj;
        const float* xv = kh ? hl_s : hs_s;
        const float* Wc = WTO + (size_t)kh * 512 * 512 + o;
#pragma unroll 32
        for (int k = 0; k < 512; ++k)
          acc = fmaf(xv[k], Wc[(size_t)k * 512], acc);
        if (kh == 1) partF[oj] = acc;
      }
      __syncthreads();
      if (t < 256) {
        const int o = oh * 256 + t;
        hbuf[(size_t)b * 512 + o] = tanhf(acc + partF[t] + p.bho[o]);
      }
    }
    gsync(ub, ++tgt, blk);
  }

  // ---- epilogue: hF, cF ----
  {
    int idx = blk * 1024 + t;
    if (idx < Bn * Hn) {
      p.out[OUT_HF + idx] = hbuf[idx];
      p.out[OUT_CF + idx] = cbuf[idx];
    }
  }
}

extern "C" void kernel_launch(void* const* d_in, const int* in_sizes, int n_in,
                              void* d_out, int out_size, void* d_ws, size_t ws_size,
                              hipStream_t stream) {
  (void)in_sizes; (void)n_in; (void)out_size; (void)ws_size;
  const float* emb     = (const float*)d_in[0];
  const float* dec0    = (const float*)d_in[1];
  const float* h0      = (const float*)d_in[2];
  const float* c0      = (const float*)d_in[3];
  const float* context = (const float*)d_in[4];
  const float* Wih     = (const float*)d_in[5];
  const float* bih     = (const float*)d_in[6];
  const float* Whh     = (const float*)d_in[7];
  const float* bhh     = (const float*)d_in[8];
  const float* Who     = (const float*)d_in[9];
  const float* bho     = (const float*)d_in[10];
  const float* Wa_in   = (const float*)d_in[11];
  const float* ba_in   = (const float*)d_in[12];
  const float* Wa_ctx  = (const float*)d_in[13];
  const float* ba_ctx  = (const float*)d_in[14];
  const float* V       = (const float*)d_in[15];
  float* ws  = (float*)d_ws;
  float* out = (float*)d_out;

  hipMemsetAsync(d_ws, 0, 32768, stream);   // barrier flags + gen

  hipLaunchKernelGGL(ctx_precompute, dim3(4096), dim3(256), 0, stream,
                     context, Wa_ctx, ba_ctx, ws);
  hipLaunchKernelGGL(transpose_w, dim3(192), dim3(256), 0, stream,
                     Wa_in, Who, ws);

  PParams prm{emb, dec0, h0, c0, Wih, bih, Whh, bhh, Who, bho, Wa_in, ba_in, V, ws, out};
  void* args[] = {&prm};
  hipLaunchCooperativeKernel((const void*)pdecoder_main, dim3(256), dim3(1024),
                             args, 0, stream);
}

// Round 5
// 36471.472 us; speedup vs baseline: 2.3556x; 2.3556x over previous
//
#include <hip/hip_runtime.h>
#include <math.h>

namespace {
constexpr int Bn = 128, Ln = 256, En = 512, Hn = 512;

// ws layout (float offsets). First 8192 floats = barrier flags (256 x 64B) + gen.
constexpr long WS_CTX  = 8192;                       // [B][L][H] = ctx[b,l,o]
constexpr long WS_H    = WS_CTX + (long)Bn * Ln * Hn;
constexpr long WS_C    = WS_H   + (long)Bn * Hn;
constexpr long WS_HL   = WS_C   + (long)Bn * Hn;
constexpr long WS_INP  = WS_HL  + (long)Bn * Hn;
constexpr long WS_HS   = WS_INP + (long)Bn * Hn;
constexpr long WS_DEC  = WS_HS  + (long)Bn * Hn;
constexpr long WS_ATT  = WS_DEC + (long)Bn * En;
constexpr long WS_MASK = WS_ATT + (long)Bn * Ln;

// out layout (float offsets)
constexpr long OUT_PTR = (long)Bn * Ln * Ln;   // 8388608
constexpr long OUT_HF  = OUT_PTR + (long)Bn * Ln;
constexpr long OUT_CF  = OUT_HF + (long)Bn * Hn;
}

struct PParams {
  const float *emb, *dec0, *h0, *c0;
  const float *Wih, *bih, *Whh, *bhh;
  const float *Who, *bho, *Wa_in, *ba_in, *V;
  float *ws, *out;
};

// ---------- flag-array grid barrier (no RMW serialization) -------------------
__device__ __forceinline__ void gsync(unsigned* ub, unsigned target, int blk) {
  __syncthreads();
  unsigned* flags = ub;            // flags[b] at ub[b*16] (64B apart)
  unsigned* gen   = ub + 4096;
  const int t = threadIdx.x;
  if (blk == 0) {
    for (;;) {
      unsigned v = (t > 0 && t < 256)
          ? __hip_atomic_load(&flags[t * 16], __ATOMIC_RELAXED, __HIP_MEMORY_SCOPE_AGENT)
          : target;
      int cnt = __syncthreads_count((int)(v >= target));
      if (cnt == (int)blockDim.x) break;
      __builtin_amdgcn_s_sleep(2);
    }
    __builtin_amdgcn_fence(__ATOMIC_ACQUIRE, "agent");
    if (t == 0)
      __hip_atomic_store(gen, target, __ATOMIC_RELEASE, __HIP_MEMORY_SCOPE_AGENT);
  } else {
    if (t == 0) {
      __hip_atomic_store(&flags[blk * 16], target, __ATOMIC_RELEASE, __HIP_MEMORY_SCOPE_AGENT);
      while (__hip_atomic_load(gen, __ATOMIC_RELAXED, __HIP_MEMORY_SCOPE_AGENT) < target)
        __builtin_amdgcn_s_sleep(2);
      (void)__hip_atomic_load(gen, __ATOMIC_ACQUIRE, __HIP_MEMORY_SCOPE_AGENT);
    }
  }
  __syncthreads();
}

// ---------------- ctx precompute: ctx[b,l,o] = context[b,l,:]·Wa_ctx[o,:] + ba_ctx[o]
__launch_bounds__(256)
__global__ void ctx_precompute(const float* __restrict__ context,
                               const float* __restrict__ Wa,
                               const float* __restrict__ ba,
                               float* __restrict__ ws) {
  __shared__ __align__(16) float As[16 * 68];
  __shared__ __align__(16) float Wsm[16 * 68];
  float* ctx = ws + WS_CTX;
  const int mt = blockIdx.x >> 3;
  const int nt = blockIdx.x & 7;
  const int t = threadIdx.x;
  const int tm = t & 15, tn = t >> 4;
  float acc00=0,acc01=0,acc02=0,acc03=0, acc10=0,acc11=0,acc12=0,acc13=0;
  float acc20=0,acc21=0,acc22=0,acc23=0, acc30=0,acc31=0,acc32=0,acc33=0;

  for (int kt = 0; kt < 32; ++kt) {
    __syncthreads();
    {
      const int m = t >> 2, k4 = t & 3;
      float4 a = *(const float4*)(context + (size_t)(mt * 64 + m) * 512 + kt * 16 + k4 * 4);
      As[(k4*4+0)*68 + m] = a.x; As[(k4*4+1)*68 + m] = a.y;
      As[(k4*4+2)*68 + m] = a.z; As[(k4*4+3)*68 + m] = a.w;
      float4 w = *(const float4*)(Wa + (size_t)(nt * 64 + m) * 512 + kt * 16 + k4 * 4);
      Wsm[(k4*4+0)*68 + m] = w.x; Wsm[(k4*4+1)*68 + m] = w.y;
      Wsm[(k4*4+2)*68 + m] = w.z; Wsm[(k4*4+3)*68 + m] = w.w;
    }
    __syncthreads();
#pragma unroll
    for (int k = 0; k < 16; ++k) {
      float4 a4 = *(const float4*)(As + k * 68 + tm * 4);
      float4 b4 = *(const float4*)(Wsm + k * 68 + tn * 4);
      acc00 = fmaf(a4.x, b4.x, acc00); acc01 = fmaf(a4.x, b4.y, acc01);
      acc02 = fmaf(a4.x, b4.z, acc02); acc03 = fmaf(a4.x, b4.w, acc03);
      acc10 = fmaf(a4.y, b4.x, acc10); acc11 = fmaf(a4.y, b4.y, acc11);
      acc12 = fmaf(a4.y, b4.z, acc12); acc13 = fmaf(a4.y, b4.w, acc13);
      acc20 = fmaf(a4.z, b4.x, acc20); acc21 = fmaf(a4.z, b4.y, acc21);
      acc22 = fmaf(a4.z, b4.z, acc22); acc23 = fmaf(a4.z, b4.w, acc23);
      acc30 = fmaf(a4.w, b4.x, acc30); acc31 = fmaf(a4.w, b4.y, acc31);
      acc32 = fmaf(a4.w, b4.z, acc32); acc33 = fmaf(a4.w, b4.w, acc33);
    }
  }
  const int col = nt * 64 + tn * 4;
  float4 bias = *(const float4*)(ba + col);
  float4 o0 = {acc00 + bias.x, acc01 + bias.y, acc02 + bias.z, acc03 + bias.w};
  float4 o1 = {acc10 + bias.x, acc11 + bias.y, acc12 + bias.z, acc13 + bias.w};
  float4 o2 = {acc20 + bias.x, acc21 + bias.y, acc22 + bias.z, acc23 + bias.w};
  float4 o3 = {acc30 + bias.x, acc31 + bias.y, acc32 + bias.z, acc33 + bias.w};
  const size_t base = (size_t)(mt * 64 + tm * 4) * 512 + col;
  *(float4*)(ctx + base + 0 * 512) = o0;
  *(float4*)(ctx + base + 1 * 512) = o1;
  *(float4*)(ctx + base + 2 * 512) = o2;
  *(float4*)(ctx + base + 3 * 512) = o3;
}

// --------- persistent main loop: 256 blocks x 1024 threads (1/CU, 16 waves) --
// R2's 5-phase structure. B and F now use A's proven batched shape:
// 16 bt(8 b-rows) x 16 ot(32 o-cols), LDS-staged swizzled x-tile, 8-way
// wave-dedup'd W row reads (8 distinct lines/instr instead of 64).
// All per-output fma sequences / trees / tie rules / combines are bit-exact
// clones of the passing R2 kernel.
__launch_bounds__(1024, 4)
__global__ void pdecoder_main(PParams p) {
  __shared__ __align__(16) float smem[8192];   // 32 KB

  float* ws = p.ws;
  unsigned* ub = (unsigned*)ws;
  unsigned tgt = 0;
  const int t = threadIdx.x, blk = blockIdx.x;

  float* ctx    = ws + WS_CTX;
  float* hbuf   = ws + WS_H;
  float* cbuf   = ws + WS_C;
  float* hlbuf  = ws + WS_HL;
  float* inpbuf = ws + WS_INP;
  float* hsbuf  = ws + WS_HS;
  float* decbuf = ws + WS_DEC;
  float* attbuf = ws + WS_ATT;
  float* maskbuf= ws + WS_MASK;

  // ---- init state (ws poisoned every call) ----
  {
    int idx = blk * 1024 + t;
    if (idx < Bn * Hn) { hbuf[idx] = p.h0[idx]; cbuf[idx] = p.c0[idx]; }
    if (idx < Bn * En) decbuf[idx] = p.dec0[idx];
    if (idx < Bn * Ln) maskbuf[idx] = 1.0f;
  }
  gsync(ub, ++tgt, blk);

  for (int step = 0; step < Ln; ++step) {
    // ===== Phase A: gates = dec@Wih^T + h@Whh^T + b; LSTM elementwise =======
    // (verbatim R2: conflict-free 8-row swizzled tile, K sequential)
    {
      const int bt = blk >> 4, gt = blk & 15;
      const int bi = t & 7, cg = t >> 3;          // cg 0..127 = g*32 + j0
      const int j0 = cg & 31, g = cg >> 5;
      const int gc = g * 512 + gt * 32 + j0;
      const int r = t >> 6, ks = t & 63;          // staging (t<512): row, col
      float4* Xs = (float4*)smem;                 // [8][64] float4, swizzled
      float acc = 0.f;
      float4 pre;
      if (t < 512) pre = ((const float4*)(decbuf + (size_t)(bt * 8 + r) * 512))[ks];
#pragma unroll
      for (int kt = 0; kt < 4; ++kt) {
        __syncthreads();
        if (t < 512) Xs[r * 64 + (ks ^ r)] = pre;
        __syncthreads();
        if (t < 512 && kt < 3) {
          const float* src = (kt + 1 < 2) ? decbuf : hbuf;
          pre = ((const float4*)(src + (size_t)(bt * 8 + r) * 512 + ((kt + 1) & 1) * 256))[ks];
        }
        const float4* W4 = (const float4*)(((kt < 2) ? p.Wih : p.Whh) + (size_t)gc * 512 + (kt & 1) * 256);
#pragma unroll 8
        for (int k4 = 0; k4 < 64; ++k4) {
          float4 x = Xs[bi * 64 + (k4 ^ bi)];
          float4 w = W4[k4];
          acc = fmaf(x.x, w.x, acc); acc = fmaf(x.y, w.y, acc);
          acc = fmaf(x.z, w.z, acc); acc = fmaf(x.w, w.w, acc);
        }
      }
      __syncthreads();
      float* gs = smem + 4096;                    // [8][132]
      gs[bi * 132 + cg] = acc + p.bih[gc] + p.bhh[gc];
      __syncthreads();
      if (t < 256) {
        const int j = t & 31, bi2 = t >> 5;
        float ig = gs[bi2 * 132 + j];
        float fg = gs[bi2 * 132 + 32 + j];
        float gg = gs[bi2 * 132 + 64 + j];
        float og = gs[bi2 * 132 + 96 + j];
        const int b = bt * 8 + bi2, h = gt * 32 + j;
        float cold = cbuf[b * 512 + h];
        float is = 1.f / (1.f + expf(-ig));
        float fs = 1.f / (1.f + expf(-fg));
        float os = 1.f / (1.f + expf(-og));
        float ct = fs * cold + is * tanhf(gg);
        float hl = os * tanhf(ct);
        cbuf[b * 512 + h] = ct;
        hlbuf[b * 512 + h] = hl;
      }
    }
    gsync(ub, ++tgt, blk);

    // ===== Phase B: inp = hl @ Wa_in^T + ba_in (batched, dedup'd rows) ======
    // 16 bt(8 b-rows) x 16 ot(32 o-cols); thread-per-output, K sequential
    // (kt 0..1, k4 0..63, xyzw) == R2's k 0..511 ascending — identical bits.
    // Wave = 8 bi x 8 oj -> 8 distinct W lines/instr (dedup'd).
    {
      const int bt = blk >> 4, ot = blk & 15;
      const int bi = t & 7, oj = t >> 3;          // compute valid for t<256
      const int o = ot * 32 + oj;
      const int r = t >> 6, ks = t & 63;          // staging (t<512)
      float4* Xs = (float4*)smem;                 // [8][64] float4, swizzled
      float acc = 0.f;
      float4 pre;
      if (t < 512) pre = ((const float4*)(hlbuf + (size_t)(bt * 8 + r) * 512))[ks];
#pragma unroll
      for (int kt = 0; kt < 2; ++kt) {
        __syncthreads();
        if (t < 512) Xs[r * 64 + (ks ^ r)] = pre;
        __syncthreads();
        if (t < 512 && kt == 0)
          pre = ((const float4*)(hlbuf + (size_t)(bt * 8 + r) * 512 + 256))[ks];
        if (t < 256) {
          const float4* Wr = (const float4*)(p.Wa_in + (size_t)o * 512 + kt * 256);
#pragma unroll 8
          for (int k4 = 0; k4 < 64; ++k4) {
            float4 x = Xs[bi * 64 + (k4 ^ bi)];
            float4 w = Wr[k4];
            acc = fmaf(x.x, w.x, acc); acc = fmaf(x.y, w.y, acc);
            acc = fmaf(x.z, w.z, acc); acc = fmaf(x.w, w.w, acc);
          }
        }
      }
      if (t < 256) inpbuf[(size_t)(bt * 8 + bi) * 512 + o] = acc + p.ba_in[o];
    }
    gsync(ub, ++tgt, blk);

    // ===== Phase C: att[b,l] = sum_h V[h] tanh(inp+ctx), mask-skipped =======
    // (R2-verbatim: 2 blocks per b, 128 l each, 16 waves x 8 l.)
    {
      const int b = blk >> 1, ph = blk & 1;
      float* inp_s = smem;          // 512
      float* V_s   = smem + 512;    // 512
      if (t < 512) { inp_s[t] = inpbuf[b * 512 + t]; V_s[t] = p.V[t]; }
      __syncthreads();
      const int w = t >> 6, lane = t & 63;
      const float4* inp4 = (const float4*)inp_s;
      const float4* V4   = (const float4*)V_s;
      float4 i0 = inp4[lane],  i1 = inp4[64 + lane];
      float4 v0 = V4[lane],    v1 = V4[64 + lane];
      for (int i = 0; i < 8; ++i) {
        const int l = ph * 128 + w * 8 + i;
        float msk = maskbuf[b * 256 + l];      // wave-uniform
        if (msk == 0.f) {
          if (lane == 0) attbuf[b * 256 + l] = -INFINITY;
          continue;
        }
        const float4* row = (const float4*)(ctx + (size_t)(b * 256 + l) * 512);
        float4 c0 = row[lane], c1 = row[64 + lane];
        float a;
        a = v0.x * tanhf(i0.x + c0.x);
        a = fmaf(v0.y, tanhf(i0.y + c0.y), a);
        a = fmaf(v0.z, tanhf(i0.z + c0.z), a);
        a = fmaf(v0.w, tanhf(i0.w + c0.w), a);
        a = fmaf(v1.x, tanhf(i1.x + c1.x), a);
        a = fmaf(v1.y, tanhf(i1.y + c1.y), a);
        a = fmaf(v1.z, tanhf(i1.z + c1.z), a);
        a = fmaf(v1.w, tanhf(i1.w + c1.w), a);
#pragma unroll
        for (int off = 32; off > 0; off >>= 1) a += __shfl_xor(a, off, 64);
        if (lane == 0) attbuf[b * 256 + l] = a;
      }
    }
    gsync(ub, ++tgt, blk);

    // ===== Phase E: tree softmax + argmax + outputs + compacted hs ==========
    {
      const int b = blk >> 1, ph = blk & 1;
      float* att_s   = smem;               // 256 (reused as scan after alpha)
      float* val_s   = smem + 256;         // 256
      int*   idx_s   = (int*)(smem + 512); // 256 (argmax idx, then compact list)
      float* alpha_s = smem + 768;         // 256
      float* part_s  = smem + 1024;        // 256
      if (t < 256) {
        float a = attbuf[b * 256 + t];
        att_s[t] = a; val_s[t] = a; idx_s[t] = t;
      }
      __syncthreads();
      for (int s = 128; s > 0; s >>= 1) {
        if (t < s) {
          float v1 = val_s[t], v2 = val_s[t + s];
          int   i1 = idx_s[t], i2 = idx_s[t + s];
          if (v2 > v1 || (v2 == v1 && i2 < i1)) { val_s[t] = v2; idx_s[t] = i2; }
        }
        __syncthreads();
      }
      const float m = val_s[0];
      const int am = idx_s[0];
      __syncthreads();
      if (t < 256) {
        float e = expf(att_s[t] - m);   // exp(-inf)=0 for masked
        alpha_s[t] = e; val_s[t] = e;
      }
      __syncthreads();
      for (int s = 128; s > 0; s >>= 1) {
        if (t < s) val_s[t] += val_s[t + s];
        __syncthreads();
      }
      const float Z = val_s[0];
      __syncthreads();
      if (t < 256) alpha_s[t] = alpha_s[t] / Z;
      __syncthreads();
      if (ph == 0) {
        if (t < 256) p.out[(size_t)b * Ln * Ln + (size_t)step * Ln + t] = alpha_s[t];
        if (t == 0) {
          p.out[OUT_PTR + (size_t)b * Ln + step] = (float)am;
          maskbuf[b * 256 + am] = 0.f;
        }
        if (t < 512) decbuf[b * 512 + t] = p.emb[((size_t)(b * 256) + am) * 512 + t];
      }
      // ---- order-preserving compaction of {l : alpha_s[l] != 0} -----------
      // Same skip condition as R2's branch (al != 0) -> per-(h,lp) fmaf
      // subsequence is bit-identical; loads unconditional + pipelined.
      if (t < 256) att_s[t] = (alpha_s[t] != 0.f) ? 1.f : 0.f;
      __syncthreads();
      for (int s = 1; s < 256; s <<= 1) {          // Hillis-Steele inclusive
        float add = 0.f;
        if (t < 256 && t >= s) add = att_s[t - s];
        __syncthreads();
        if (t < 256) att_s[t] += add;
        __syncthreads();
      }
      if (t < 256 && alpha_s[t] != 0.f) idx_s[(int)att_s[t] - 1] = t;
      __syncthreads();
      const int cnt0 = (int)att_s[127];
      const int cntA = (int)att_s[255];
      // hs[b, ph*256+hi] over 2 l-halves (compact [0,cnt0) and [cnt0,cntA)),
      // pairwise combined — R2-exact order.
      const int hi = t & 255, lp = (t >> 8) & 1;
      const int h = ph * 256 + hi;
      float acc = 0.f;
      if (t < 512) {
        const float* cb = ctx + (size_t)b * 256 * 512 + h;
        int j = lp ? cnt0 : 0;
        const int jhi = lp ? cntA : cnt0;
        for (; j + 8 <= jhi; j += 8) {
          int l0 = idx_s[j+0], l1 = idx_s[j+1], l2 = idx_s[j+2], l3 = idx_s[j+3];
          int l4 = idx_s[j+4], l5 = idx_s[j+5], l6 = idx_s[j+6], l7 = idx_s[j+7];
          float a0 = alpha_s[l0], a1 = alpha_s[l1], a2 = alpha_s[l2], a3 = alpha_s[l3];
          float a4 = alpha_s[l4], a5 = alpha_s[l5], a6 = alpha_s[l6], a7 = alpha_s[l7];
          float c0 = cb[(size_t)l0 * 512], c1 = cb[(size_t)l1 * 512];
          float c2 = cb[(size_t)l2 * 512], c3 = cb[(size_t)l3 * 512];
          float c4 = cb[(size_t)l4 * 512], c5 = cb[(size_t)l5 * 512];
          float c6 = cb[(size_t)l6 * 512], c7 = cb[(size_t)l7 * 512];
          acc = fmaf(a0, c0, acc); acc = fmaf(a1, c1, acc);
          acc = fmaf(a2, c2, acc); acc = fmaf(a3, c3, acc);
          acc = fmaf(a4, c4, acc); acc = fmaf(a5, c5, acc);
          acc = fmaf(a6, c6, acc); acc = fmaf(a7, c7, acc);
        }
        for (; j < jhi; ++j) {
          int l = idx_s[j];
          acc = fmaf(alpha_s[l], cb[(size_t)l * 512], acc);
        }
      }
      if (t < 512 && lp == 1) part_s[hi] = acc;
      __syncthreads();
      if (t < 512 && lp == 0) hsbuf[(size_t)b * 512 + h] = acc + part_s[hi];
    }
    gsync(ub, ++tgt, blk);

    // ===== Phase F: h = tanh([hs, hl] @ Who^T + bho) — batched pairwise =====
    // 16 bt x 16 ot; 512 threads = 8 bi x 32 oj x 2 kh. kh=0 sums the hs-half
    // (k 0..511 ascending), kh=1 the hl-half; combine (acc0+acc1)+bho, tanhf
    // — exact R2 chain. Wave = 8 bi x 8 (oj,kh) -> 8 distinct W lines/instr.
    {
      const int bt = blk >> 4, ot = blk & 15;
      const int bi = t & 7, oj = (t >> 3) & 31, kh = t >> 8;  // valid t<512
      const int o = ot * 32 + oj;
      const int r = t >> 6, ks = t & 63;          // staging (t<512)
      float4* Xs = (float4*)smem;                 // [8][64] float4, swizzled
      float acc = 0.f;
      float4 pre;
      if (t < 512) pre = ((const float4*)(hsbuf + (size_t)(bt * 8 + r) * 512))[ks];
#pragma unroll
      for (int kt = 0; kt < 4; ++kt) {
        __syncthreads();
        if (t < 512) Xs[r * 64 + (ks ^ r)] = pre;
        __syncthreads();
        if (t < 512 && kt < 3) {
          const float* src = (kt + 1 < 2) ? hsbuf : hlbuf;
          pre = ((const float4*)(src + (size_t)(bt * 8 + r) * 512 + ((kt + 1) & 1) * 256))[ks];
        }
        if (t < 512 && (kt >> 1) == kh) {
          const float4* Wr = (const float4*)(p.Who + (size_t)o * 1024 + (size_t)kh * 512 + (kt & 1) * 256);
#pragma unroll 8
          for (int k4 = 0; k4 < 64; ++k4) {
            float4 x = Xs[bi * 64 + (k4 ^ bi)];
            float4 w = Wr[k4];
            acc = fmaf(x.x, w.x, acc); acc = fmaf(x.y, w.y, acc);
            acc = fmaf(x.z, w.z, acc); acc = fmaf(x.w, w.w, acc);
          }
        }
      }
      __syncthreads();
      float* part = smem + 4096;                  // [8][68]
      if (t < 512) part[bi * 68 + kh * 32 + oj] = acc;
      __syncthreads();
      if (t < 256) {
        const int bi2 = t & 7, oj2 = t >> 3;      // 0..31
        float v = part[bi2 * 68 + oj2] + part[bi2 * 68 + 32 + oj2];
        const int o2 = ot * 32 + oj2, bb = bt * 8 + bi2;
        hbuf[(size_t)bb * 512 + o2] = tanhf(v + p.bho[o2]);
      }
    }
    gsync(ub, ++tgt, blk);
  }

  // ---- epilogue: hF, cF ----
  {
    int idx = blk * 1024 + t;
    if (idx < Bn * Hn) {
      p.out[OUT_HF + idx] = hbuf[idx];
      p.out[OUT_CF + idx] = cbuf[idx];
    }
  }
}

extern "C" void kernel_launch(void* const* d_in, const int* in_sizes, int n_in,
                              void* d_out, int out_size, void* d_ws, size_t ws_size,
                              hipStream_t stream) {
  (void)in_sizes; (void)n_in; (void)out_size; (void)ws_size;
  const float* emb     = (const float*)d_in[0];
  const float* dec0    = (const float*)d_in[1];
  const float* h0      = (const float*)d_in[2];
  const float* c0      = (const float*)d_in[3];
  const float* context = (const float*)d_in[4];
  const float* Wih     = (const float*)d_in[5];
  const float* bih     = (const float*)d_in[6];
  const float* Whh     = (const float*)d_in[7];
  const float* bhh     = (const float*)d_in[8];
  const float* Who     = (const float*)d_in[9];
  const float* bho     = (const float*)d_in[10];
  const float* Wa_in   = (const float*)d_in[11];
  const float* ba_in   = (const float*)d_in[12];
  const float* Wa_ctx  = (const float*)d_in[13];
  const float* ba_ctx  = (const float*)d_in[14];
  const float* V       = (const float*)d_in[15];
  float* ws  = (float*)d_ws;
  float* out = (float*)d_out;

  hipMemsetAsync(d_ws, 0, 32768, stream);   // barrier flags + gen

  hipLaunchKernelGGL(ctx_precompute, dim3(4096), dim3(256), 0, stream,
                     context, Wa_ctx, ba_ctx, ws);

  PParams prm{emb, dec0, h0, c0, Wih, bih, Whh, bhh, Who, bho, Wa_in, ba_in, V, ws, out};
  void* args[] = {&prm};
  hipLaunchCooperativeKernel((const void*)pdecoder_main, dim3(256), dim3(1024),
                             args, 0, stream);
}